// Round 1
// 205.206 us; speedup vs baseline: 1.0220x; 1.0220x over previous
//
#include <hip/hip_runtime.h>

#define S_TOKENS 16384
#define DMODEL   2048
#define NE       8
#define CAPACITY 2560
#define AUXC     0.01f

// ws layout (4-byte units):
//   [0, 16384)      int    expert idx per token
//   [16384, 32768)  float  gate per token
//   [32768, 34816)  int    exclusive prefix per 64-token span (256 spans x 8 experts)
//   [34816, 40960)  float  per-block partials: 512 blocks x {psum[8], zsum, pad[3]}

__global__ __launch_bounds__(512, 4) void logits_kernel(
    const float* __restrict__ x, const float* __restrict__ W,
    int* __restrict__ idx_out, float* __restrict__ gate_out,
    float* __restrict__ bsums) {
    // W staged per-expert as float4: WE[e*512 + j] = W[e][4j..4j+3].
    // Reads are lane-stride 16B (conflict-free); staging is a coalesced float4 copy.
    __shared__ float4 WE[NE * 512];   // 64 KB

    const int tid  = threadIdx.x;
    const int wave = tid >> 6;
    const int lane = tid & 63;

    {
        const float4* __restrict__ Wf4 = (const float4*)W;
        #pragma unroll
        for (int i = 0; i < 8; ++i) WE[i * 512 + tid] = Wf4[i * 512 + tid];
    }
    __syncthreads();

    // 4 consecutive tokens per wave -> each W LDS read feeds 4 tokens (4x less LDS/token)
    const int t0 = blockIdx.x * 32 + wave * 4;
    const float4* __restrict__ xr0 = (const float4*)x + (size_t)(t0 + 0) * (DMODEL / 4);
    const float4* __restrict__ xr1 = (const float4*)x + (size_t)(t0 + 1) * (DMODEL / 4);
    const float4* __restrict__ xr2 = (const float4*)x + (size_t)(t0 + 2) * (DMODEL / 4);
    const float4* __restrict__ xr3 = (const float4*)x + (size_t)(t0 + 3) * (DMODEL / 4);

    float acc[4][NE];
    #pragma unroll
    for (int t = 0; t < 4; ++t) {
        #pragma unroll
        for (int e = 0; e < NE; ++e) acc[t][e] = 0.0f;
    }

    #pragma unroll 2
    for (int it = 0; it < (DMODEL / 4) / 64; ++it) {   // 8 iterations
        const int j = it * 64 + lane;
        float4 xv0 = xr0[j];
        float4 xv1 = xr1[j];
        float4 xv2 = xr2[j];
        float4 xv3 = xr3[j];
        #pragma unroll
        for (int e = 0; e < NE; ++e) {
            float4 w = WE[e * 512 + j];
            acc[0][e] += xv0.x * w.x + xv0.y * w.y + xv0.z * w.z + xv0.w * w.w;
            acc[1][e] += xv1.x * w.x + xv1.y * w.y + xv1.z * w.z + xv1.w * w.w;
            acc[2][e] += xv2.x * w.x + xv2.y * w.y + xv2.z * w.z + xv2.w * w.w;
            acc[3][e] += xv3.x * w.x + xv3.y * w.y + xv3.z * w.z + xv3.w * w.w;
        }
    }

    // Value-halving reduction: after 3 halving steps + 3 finish steps, every lane
    // holds the FULL logit of expert eL = lane>>3 (replicated over the 8 lanes
    // sharing bits 3..5). Softmax/argmax then reduce across offs {8,16,32}.
    const int  eL = lane >> 3;
    const bool b5 = (lane & 32) != 0;
    const bool b4 = (lane & 16) != 0;
    const bool b3 = (lane & 8)  != 0;

    float pacc = 0.0f;   // prob mass for expert eL (only lanes with (lane&7)==0 count it)
    float zacc = 0.0f;   // lane 0: sum of logsumexp^2

    #pragma unroll
    for (int t = 0; t < 4; ++t) {
        float b[4];
        #pragma unroll
        for (int i = 0; i < 4; ++i) {
            float keepv = b5 ? acc[t][i + 4] : acc[t][i];
            float sendv = b5 ? acc[t][i]     : acc[t][i + 4];
            b[i] = keepv + __shfl_xor(sendv, 32);
        }
        float c[2];
        #pragma unroll
        for (int i = 0; i < 2; ++i) {
            float keepv = b4 ? b[i + 2] : b[i];
            float sendv = b4 ? b[i]     : b[i + 2];
            c[i] = keepv + __shfl_xor(sendv, 16);
        }
        float keepv = b3 ? c[1] : c[0];
        float sendv = b3 ? c[0] : c[1];
        float d = keepv + __shfl_xor(sendv, 8);
        // finish partial sums across lane bits 0..2 (same-expert lanes)
        d += __shfl_xor(d, 1);
        d += __shfl_xor(d, 2);
        d += __shfl_xor(d, 4);

        // softmax / argmax across the 8 experts (lane bits 3..5)
        float m = d;
        m = fmaxf(m, __shfl_xor(m, 8));
        m = fmaxf(m, __shfl_xor(m, 16));
        m = fmaxf(m, __shfl_xor(m, 32));
        int cand = (d == m) ? eL : NE;       // first-max semantics via min-index
        cand = min(cand, __shfl_xor(cand, 8));
        cand = min(cand, __shfl_xor(cand, 16));
        cand = min(cand, __shfl_xor(cand, 32));
        float p = expf(d - m);
        float z = p;
        z += __shfl_xor(z, 8);
        z += __shfl_xor(z, 16);
        z += __shfl_xor(z, 32);
        float gate = 1.0f / z;               // exp(max-m)/z with m==max

        if ((lane & 7) == 0) pacc += p * gate;   // p/z = prob of expert eL
        if (lane == 0) {
            const int token = t0 + t;
            idx_out[token]  = cand;
            gate_out[token] = gate;
            float lz = m + logf(z);
            zacc += lz * lz;
        }
    }

    // block-level reduction into this block's private slot (no atomics, no init kernel)
    __syncthreads();
    float* red = (float*)WE;        // [wave*8 + e], 64 floats
    float* zrd = (float*)WE + 64;   // [wave], 8 floats
    if ((lane & 7) == 0) red[wave * 8 + eL] = pacc;
    if (lane == 0)       zrd[wave] = zacc;
    __syncthreads();
    if (tid < NE) {
        float s = 0.0f;
        #pragma unroll
        for (int w = 0; w < 8; ++w) s += red[w * 8 + tid];
        bsums[blockIdx.x * 12 + tid] = s;
    } else if (tid == NE) {
        float s = 0.0f;
        #pragma unroll
        for (int w = 0; w < 8; ++w) s += zrd[w];
        bsums[blockIdx.x * 12 + NE] = s;
    }
}

__global__ __launch_bounds__(256, 1) void scan_kernel(
    const int* __restrict__ idx, int* __restrict__ prefix,
    const float* __restrict__ bsums, float* __restrict__ aux_out) {
    __shared__ int   arr[NE][256];
    __shared__ float bs[9][256];
    __shared__ float ptot[9];
    const int t = threadIdx.x;

    // stage per-block partials (512 blocks x 9 values), pairwise-added
    #pragma unroll
    for (int q = 0; q < 9; ++q)
        bs[q][t] = bsums[t * 12 + q] + bsums[(t + 256) * 12 + q];

    // per-thread histogram of tokens [t*64, t*64+64), byte-packed (max 64 < 256)
    unsigned clo = 0, chi = 0;
    const int4* __restrict__ idx4 = (const int4*)idx;
    #pragma unroll 4
    for (int i = 0; i < 16; ++i) {
        int4 v = idx4[t * 16 + i];
        if (v.x < 4) clo += 1u << (8 * v.x); else chi += 1u << (8 * (v.x - 4));
        if (v.y < 4) clo += 1u << (8 * v.y); else chi += 1u << (8 * (v.y - 4));
        if (v.z < 4) clo += 1u << (8 * v.z); else chi += 1u << (8 * (v.z - 4));
        if (v.w < 4) clo += 1u << (8 * v.w); else chi += 1u << (8 * (v.w - 4));
    }
    int cnt[8];
    cnt[0] = clo & 255; cnt[1] = (clo >> 8) & 255; cnt[2] = (clo >> 16) & 255; cnt[3] = clo >> 24;
    cnt[4] = chi & 255; cnt[5] = (chi >> 8) & 255; cnt[6] = (chi >> 16) & 255; cnt[7] = chi >> 24;
    #pragma unroll
    for (int e = 0; e < NE; ++e) arr[e][t] = cnt[e];
    __syncthreads();

    // wave 0: finish the 9-value global reduction while other waves head to the scan
    if (t < 64) {
        float s[9];
        #pragma unroll
        for (int q = 0; q < 9; ++q)
            s[q] = bs[q][t] + bs[q][t + 64] + bs[q][t + 128] + bs[q][t + 192];
        #pragma unroll
        for (int off = 32; off > 0; off >>= 1) {
            #pragma unroll
            for (int q = 0; q < 9; ++q) s[q] += __shfl_xor(s[q], off);
        }
        if (t == 0) {
            #pragma unroll
            for (int q = 0; q < 9; ++q) ptot[q] = s[q];
        }
    }

    // Hillis-Steele inclusive scan over 256 spans, all 8 experts per step
    for (int off = 1; off < 256; off <<= 1) {
        int v[8];
        #pragma unroll
        for (int e = 0; e < NE; ++e) v[e] = (t >= off) ? arr[e][t - off] : 0;
        __syncthreads();
        #pragma unroll
        for (int e = 0; e < NE; ++e) arr[e][t] += v[e];
        __syncthreads();
    }
    #pragma unroll
    for (int e = 0; e < NE; ++e) prefix[t * 8 + e] = arr[e][t] - cnt[e];

    if (t == 0) {
        float lb = 0.0f;
        #pragma unroll
        for (int e = 0; e < NE; ++e) {
            float f = (float)arr[e][255] / (float)S_TOKENS;
            float p = ptot[e] / (float)S_TOKENS;
            lb += f * p;
        }
        lb *= AUXC * (float)NE;
        float zl = AUXC * (ptot[8] / (float)S_TOKENS);
        aux_out[0] = zl + lb;
    }
}

__global__ __launch_bounds__(64, 1) void output_kernel(
    const int* __restrict__ idx, const float* __restrict__ gate,
    const int* __restrict__ prefix, float* __restrict__ out) {
    const int b = blockIdx.x;    // 256 spans of 64 tokens
    const int l = threadIdx.x;   // 64 lanes
    const int token = b * 64 + l;
    const int e = idx[token];

    unsigned long long mymask = 0;
    #pragma unroll
    for (int q = 0; q < NE; ++q) {
        unsigned long long msk = __ballot(e == q);
        if (e == q) mymask = msk;
    }
    unsigned long long lt = (1ull << l) - 1ull;
    int rank = prefix[b * 8 + e] + __popcll(mymask & lt);

    out[token] = (float)e;
    out[S_TOKENS + token] = (rank < CAPACITY) ? gate[token] : 0.0f;
}

extern "C" void kernel_launch(void* const* d_in, const int* in_sizes, int n_in,
                              void* d_out, int out_size, void* d_ws, size_t ws_size,
                              hipStream_t stream) {
    const float* x = (const float*)d_in[0];
    const float* W = (const float*)d_in[1];
    float* out = (float*)d_out;

    int*   ws_idx    = (int*)d_ws;
    float* ws_gate   = (float*)d_ws + 16384;
    int*   ws_prefix = (int*)d_ws + 32768;
    float* ws_bsums  = (float*)d_ws + 34816;   // 512 x 12 floats

    logits_kernel<<<512, 512, 0, stream>>>(x, W, ws_idx, ws_gate, ws_bsums);
    scan_kernel<<<1, 256, 0, stream>>>(ws_idx, ws_prefix, ws_bsums, out + 2 * S_TOKENS);
    output_kernel<<<256, 64, 0, stream>>>(ws_idx, ws_gate, ws_prefix, out);
}

// Round 2
// 203.298 us; speedup vs baseline: 1.0315x; 1.0094x over previous
//
#include <hip/hip_runtime.h>

#define S_TOKENS 16384
#define DMODEL   2048
#define NE       8
#define CAPACITY 2560
#define AUXC     0.01f

// ws layout (4-byte units):
//   [0, 16384)      int    expert idx per token
//   [16384, 32768)  float  gate per token
//   [34816, 40960)  float  per-block partials: 512 blocks x {psum[8], zsum, pad[3]}

__global__ __launch_bounds__(512, 4) void logits_kernel(
    const float* __restrict__ x, const float* __restrict__ W,
    int* __restrict__ idx_out, float* __restrict__ gate_out,
    float* __restrict__ bsums) {
    // W staged per-expert as float4: WE[e*512 + j] = W[e][4j..4j+3].
    __shared__ float4 WE[NE * 512];   // 64 KB

    const int tid  = threadIdx.x;
    const int wave = tid >> 6;
    const int lane = tid & 63;

    {
        const float4* __restrict__ Wf4 = (const float4*)W;
        #pragma unroll
        for (int i = 0; i < 8; ++i) WE[i * 512 + tid] = Wf4[i * 512 + tid];
    }
    __syncthreads();

    // 4 consecutive tokens per wave -> each W LDS read feeds 4 tokens
    const int t0 = blockIdx.x * 32 + wave * 4;
    const float4* __restrict__ xr0 = (const float4*)x + (size_t)(t0 + 0) * (DMODEL / 4);
    const float4* __restrict__ xr1 = (const float4*)x + (size_t)(t0 + 1) * (DMODEL / 4);
    const float4* __restrict__ xr2 = (const float4*)x + (size_t)(t0 + 2) * (DMODEL / 4);
    const float4* __restrict__ xr3 = (const float4*)x + (size_t)(t0 + 3) * (DMODEL / 4);

    float acc[4][NE];
    #pragma unroll
    for (int t = 0; t < 4; ++t) {
        #pragma unroll
        for (int e = 0; e < NE; ++e) acc[t][e] = 0.0f;
    }

    #pragma unroll 2
    for (int it = 0; it < (DMODEL / 4) / 64; ++it) {   // 8 iterations
        const int j = it * 64 + lane;
        float4 xv0 = xr0[j];
        float4 xv1 = xr1[j];
        float4 xv2 = xr2[j];
        float4 xv3 = xr3[j];
        #pragma unroll
        for (int e = 0; e < NE; ++e) {
            float4 w = WE[e * 512 + j];
            acc[0][e] += xv0.x * w.x + xv0.y * w.y + xv0.z * w.z + xv0.w * w.w;
            acc[1][e] += xv1.x * w.x + xv1.y * w.y + xv1.z * w.z + xv1.w * w.w;
            acc[2][e] += xv2.x * w.x + xv2.y * w.y + xv2.z * w.z + xv2.w * w.w;
            acc[3][e] += xv3.x * w.x + xv3.y * w.y + xv3.z * w.z + xv3.w * w.w;
        }
    }

    const int  eL = lane >> 3;
    const bool b5 = (lane & 32) != 0;
    const bool b4 = (lane & 16) != 0;
    const bool b3 = (lane & 8)  != 0;

    float pacc = 0.0f;   // prob mass for expert eL (lanes with (lane&7)==0)
    float zacc = 0.0f;   // lane 0: sum of logsumexp^2
    int4   ei = make_int4(0, 0, 0, 0);
    float4 gv = make_float4(0.f, 0.f, 0.f, 0.f);

    #pragma unroll
    for (int t = 0; t < 4; ++t) {
        float b[4];
        #pragma unroll
        for (int i = 0; i < 4; ++i) {
            float keepv = b5 ? acc[t][i + 4] : acc[t][i];
            float sendv = b5 ? acc[t][i]     : acc[t][i + 4];
            b[i] = keepv + __shfl_xor(sendv, 32);
        }
        float c[2];
        #pragma unroll
        for (int i = 0; i < 2; ++i) {
            float keepv = b4 ? b[i + 2] : b[i];
            float sendv = b4 ? b[i]     : b[i + 2];
            c[i] = keepv + __shfl_xor(sendv, 16);
        }
        float keepv = b3 ? c[1] : c[0];
        float sendv = b3 ? c[0] : c[1];
        float d = keepv + __shfl_xor(sendv, 8);
        d += __shfl_xor(d, 1);
        d += __shfl_xor(d, 2);
        d += __shfl_xor(d, 4);

        float m = d;
        m = fmaxf(m, __shfl_xor(m, 8));
        m = fmaxf(m, __shfl_xor(m, 16));
        m = fmaxf(m, __shfl_xor(m, 32));
        int cand = (d == m) ? eL : NE;       // first-max semantics via min-index
        cand = min(cand, __shfl_xor(cand, 8));
        cand = min(cand, __shfl_xor(cand, 16));
        cand = min(cand, __shfl_xor(cand, 32));
        float p = expf(d - m);
        float z = p;
        z += __shfl_xor(z, 8);
        z += __shfl_xor(z, 16);
        z += __shfl_xor(z, 32);
        float gate = 1.0f / z;               // exp(max-m)/z with m==max

        if ((lane & 7) == 0) pacc += p * gate;
        if (lane == 0) {
            if (t == 0) { ei.x = cand; gv.x = gate; }
            if (t == 1) { ei.y = cand; gv.y = gate; }
            if (t == 2) { ei.z = cand; gv.z = gate; }
            if (t == 3) { ei.w = cand; gv.w = gate; }
            float lz = m + logf(z);
            zacc += lz * lz;
        }
    }
    if (lane == 0) {
        ((int4*)idx_out)[blockIdx.x * 8 + wave]    = ei;
        ((float4*)gate_out)[blockIdx.x * 8 + wave] = gv;
    }

    // block-level reduction into this block's private slot
    __syncthreads();
    float* red = (float*)WE;        // [wave*8 + e]
    float* zrd = (float*)WE + 64;   // [wave]
    if ((lane & 7) == 0) red[wave * 8 + eL] = pacc;
    if (lane == 0)       zrd[wave] = zacc;
    __syncthreads();
    if (tid < NE) {
        float s = 0.0f;
        #pragma unroll
        for (int w = 0; w < 8; ++w) s += red[w * 8 + tid];
        bsums[blockIdx.x * 12 + tid] = s;
    } else if (tid == NE) {
        float s = 0.0f;
        #pragma unroll
        for (int w = 0; w < 8; ++w) s += zrd[w];
        bsums[blockIdx.x * 12 + NE] = s;
    }
}

// Fused scan + rank + output: one block, 1024 threads, 16 tokens per thread.
// Per-expert counts are 16-bit-field packed (2 experts per u32) through the scan.
__global__ __launch_bounds__(1024, 1) void finalize_kernel(
    const int* __restrict__ idx, const float* __restrict__ gate,
    const float* __restrict__ bsums, float* __restrict__ out) {
    __shared__ float    bs[9][256];     // staged bsums pairs
    __shared__ unsigned wtot[16][4];    // per-wave inclusive totals (packed)
    __shared__ unsigned wexc[16][4];    // per-wave exclusive offsets (packed)
    __shared__ unsigned gtot[4];        // global per-expert totals (packed)
    __shared__ float    ptot[9];

    const int t    = threadIdx.x;
    const int wave = t >> 6;
    const int lane = t & 63;

    // phase A: stage bsums partials (512 x 9, stride 12)
    if (t < 256) {
        #pragma unroll
        for (int q = 0; q < 9; ++q)
            bs[q][t] = bsums[t * 12 + q] + bsums[(t + 256) * 12 + q];
    }

    // phase B: histogram of my 16 tokens, byte-packed (max 16 per expert)
    const int4* __restrict__ idx4 = (const int4*)idx;
    int4 v0 = idx4[t * 4 + 0];
    int4 v1 = idx4[t * 4 + 1];
    int4 v2 = idx4[t * 4 + 2];
    int4 v3 = idx4[t * 4 + 3];
    unsigned clo = 0, chi = 0;
#define HACC(E) { int e_ = (E); if (e_ < 4) clo += 1u << (e_ * 8); else chi += 1u << ((e_ - 4) * 8); }
    HACC(v0.x) HACC(v0.y) HACC(v0.z) HACC(v0.w)
    HACC(v1.x) HACC(v1.y) HACC(v1.z) HACC(v1.w)
    HACC(v2.x) HACC(v2.y) HACC(v2.z) HACC(v2.w)
    HACC(v3.x) HACC(v3.y) HACC(v3.z) HACC(v3.w)
#undef HACC
    // repack bytes -> 16-bit fields: pXY = cntX | cntY<<16
    unsigned p01 = (clo & 0xFFu)         | ((clo >> 8) & 0xFFu) << 16;
    unsigned p23 = ((clo >> 16) & 0xFFu) | ((clo >> 24)       ) << 16;
    unsigned p45 = (chi & 0xFFu)         | ((chi >> 8) & 0xFFu) << 16;
    unsigned p67 = ((chi >> 16) & 0xFFu) | ((chi >> 24)       ) << 16;

    // phase C: intra-wave inclusive scan (fields <= 1024, no carry)
    unsigned i01 = p01, i23 = p23, i45 = p45, i67 = p67;
    #pragma unroll
    for (int off = 1; off < 64; off <<= 1) {
        unsigned u01 = __shfl_up(i01, off);
        unsigned u23 = __shfl_up(i23, off);
        unsigned u45 = __shfl_up(i45, off);
        unsigned u67 = __shfl_up(i67, off);
        if (lane >= off) { i01 += u01; i23 += u23; i45 += u45; i67 += u67; }
    }
    if (lane == 63) {
        wtot[wave][0] = i01; wtot[wave][1] = i23;
        wtot[wave][2] = i45; wtot[wave][3] = i67;
    }
    __syncthreads();

    // phase D: wave 0 exclusive-scans the 16 wave totals (segmented shfl, width 16)
    if (wave == 0) {
        const int k = lane >> 4;    // packed word 0..3
        const int w = lane & 15;    // wave index
        unsigned val = wtot[w][k];
        unsigned inc = val;
        #pragma unroll
        for (int off = 1; off < 16; off <<= 1) {
            unsigned u = __shfl_up(inc, off, 16);
            if (w >= off) inc += u;
        }
        wexc[w][k] = inc - val;
        if (w == 15) gtot[k] = inc;       // global totals (fields <= 16384)
    } else if (wave == 1) {
        // phase E: finish the 9-value global reduction
        float s[9];
        #pragma unroll
        for (int q = 0; q < 9; ++q)
            s[q] = bs[q][lane] + bs[q][lane + 64] + bs[q][lane + 128] + bs[q][lane + 192];
        #pragma unroll
        for (int off = 32; off > 0; off >>= 1) {
            #pragma unroll
            for (int q = 0; q < 9; ++q) s[q] += __shfl_xor(s[q], off);
        }
        if (lane == 0) {
            #pragma unroll
            for (int q = 0; q < 9; ++q) ptot[q] = s[q];
        }
    }
    __syncthreads();

    if (t == 0) {
        float lb = 0.0f;
        #pragma unroll
        for (int e = 0; e < NE; ++e) {
            float cnt_e = (float)((gtot[e >> 1] >> ((e & 1) * 16)) & 0xFFFFu);
            float f = cnt_e / (float)S_TOKENS;
            float p = ptot[e] / (float)S_TOKENS;
            lb += f * p;
        }
        lb *= AUXC * (float)NE;
        float zl = AUXC * (ptot[8] / (float)S_TOKENS);
        out[2 * S_TOKENS] = zl + lb;
    }

    // phase F: my packed exclusive prefix, then serial rank-walk of my 16 tokens
    const unsigned b01 = wexc[wave][0] + (i01 - p01);
    const unsigned b23 = wexc[wave][1] + (i23 - p23);
    const unsigned b45 = wexc[wave][2] + (i45 - p45);
    const unsigned b67 = wexc[wave][3] + (i67 - p67);

    const float4* __restrict__ gate4 = (const float4*)gate;
    float4 g0 = gate4[t * 4 + 0];
    float4 g1 = gate4[t * 4 + 1];
    float4 g2 = gate4[t * 4 + 2];
    float4 g3 = gate4[t * 4 + 3];

    unsigned llo = 0, lhi = 0;   // local byte counters (max 16)
    float4 e0, e1, e2, e3, q0, q1, q2, q3;
#define STEP(EV, GV, OE, OG) { \
    int e_ = (EV); \
    unsigned pw_ = (e_ < 4) ? ((e_ < 2) ? b01 : b23) : ((e_ < 6) ? b45 : b67); \
    int base_  = (int)((pw_ >> ((e_ & 1) * 16)) & 0xFFFFu); \
    int local_ = (int)(((e_ < 4) ? (llo >> (e_ * 8)) : (lhi >> ((e_ - 4) * 8))) & 0xFFu); \
    if (e_ < 4) llo += 1u << (e_ * 8); else lhi += 1u << ((e_ - 4) * 8); \
    OE = (float)e_; \
    OG = ((base_ + local_) < CAPACITY) ? (GV) : 0.0f; \
}
    STEP(v0.x, g0.x, e0.x, q0.x) STEP(v0.y, g0.y, e0.y, q0.y)
    STEP(v0.z, g0.z, e0.z, q0.z) STEP(v0.w, g0.w, e0.w, q0.w)
    STEP(v1.x, g1.x, e1.x, q1.x) STEP(v1.y, g1.y, e1.y, q1.y)
    STEP(v1.z, g1.z, e1.z, q1.z) STEP(v1.w, g1.w, e1.w, q1.w)
    STEP(v2.x, g2.x, e2.x, q2.x) STEP(v2.y, g2.y, e2.y, q2.y)
    STEP(v2.z, g2.z, e2.z, q2.z) STEP(v2.w, g2.w, e2.w, q2.w)
    STEP(v3.x, g3.x, e3.x, q3.x) STEP(v3.y, g3.y, e3.y, q3.y)
    STEP(v3.z, g3.z, e3.z, q3.z) STEP(v3.w, g3.w, e3.w, q3.w)
#undef STEP

    float4* __restrict__ oute = (float4*)out;
    float4* __restrict__ outg = (float4*)(out + S_TOKENS);
    oute[t * 4 + 0] = e0; oute[t * 4 + 1] = e1;
    oute[t * 4 + 2] = e2; oute[t * 4 + 3] = e3;
    outg[t * 4 + 0] = q0; outg[t * 4 + 1] = q1;
    outg[t * 4 + 2] = q2; outg[t * 4 + 3] = q3;
}

extern "C" void kernel_launch(void* const* d_in, const int* in_sizes, int n_in,
                              void* d_out, int out_size, void* d_ws, size_t ws_size,
                              hipStream_t stream) {
    const float* x = (const float*)d_in[0];
    const float* W = (const float*)d_in[1];
    float* out = (float*)d_out;

    int*   ws_idx   = (int*)d_ws;
    float* ws_gate  = (float*)d_ws + 16384;
    float* ws_bsums = (float*)d_ws + 34816;   // 512 x 12 floats

    logits_kernel<<<512, 512, 0, stream>>>(x, W, ws_idx, ws_gate, ws_bsums);
    finalize_kernel<<<1, 1024, 0, stream>>>(ws_idx, ws_gate, ws_bsums, out);
}